// Round 3
// baseline (726.707 us; speedup 1.0000x reference)
//
#include <hip/hip_runtime.h>
#include <stdint.h>

typedef unsigned short u16;
typedef __bf16 bf16x8 __attribute__((ext_vector_type(8)));
typedef float f32x4 __attribute__((ext_vector_type(4)));

#define HEADS 24
#define HD 128
#define S_LEN 2048
#define HID 3072

__device__ __forceinline__ u16 f2bf(float f) {
  union { float f; uint32_t u; } a; a.f = f;
  return (u16)((a.u + 0x7FFFu + ((a.u >> 16) & 1u)) >> 16);
}

// ---------------- f32 -> bf16 convert (vectorized) ----------------
__global__ __launch_bounds__(256) void k_f2bf(const float* __restrict__ in,
                                              u16* __restrict__ out, int n4) {
  int i = blockIdx.x * 256 + threadIdx.x;
  if (i >= n4) return;
  float4 v = ((const float4*)in)[i];
  uint2 pk;
  pk.x = (uint32_t)f2bf(v.x) | ((uint32_t)f2bf(v.y) << 16);
  pk.y = (uint32_t)f2bf(v.z) | ((uint32_t)f2bf(v.w) << 16);
  ((uint2*)out)[i] = pk;
}

// ---------------- bf16 GEMM  C[m][n] = sum_k A[m][k]*B[n][k] + bias[n] ----------------
// 128x128 tile, BK=32, 256 threads = 4 waves (2x2), each wave 64x64 (4x4 frags 16x16x32)
__global__ __launch_bounds__(256) void k_gemm_bt(
    const u16* __restrict__ A,
    const u16* __restrict__ B0, const u16* __restrict__ B1, const u16* __restrict__ B2,
    const float* __restrict__ bias0, const float* __restrict__ bias1, const float* __restrict__ bias2,
    float* __restrict__ C0, float* __restrict__ C1, float* __restrict__ C2,
    int M, int N, int K)
{
  const int z = blockIdx.z;
  const u16* __restrict__ B = (z == 0) ? B0 : (z == 1 ? B1 : B2);
  const float* __restrict__ bias = (z == 0) ? bias0 : (z == 1 ? bias1 : bias2);
  float* __restrict__ C = (z == 0) ? C0 : (z == 1 ? C1 : C2);
  const int m0 = blockIdx.x * 128, n0 = blockIdx.y * 128;
  const int tid = threadIdx.x, l = tid & 63, w = tid >> 6;
  const int wm = w >> 1, wn = w & 1;
  const int lr = l & 15, lg = l >> 4;

  __shared__ u16 Al[128 * 40];  // +8 pad: 80B row stride -> 2-way banks, 16B aligned
  __shared__ u16 Bl[128 * 40];

  f32x4 acc[4][4];
#pragma unroll
  for (int m = 0; m < 4; m++)
#pragma unroll
    for (int n = 0; n < 4; n++) acc[m][n] = f32x4{0.f, 0.f, 0.f, 0.f};

  const int sr = tid >> 2;              // staging row (0..63), rows sr and sr+64
  const int so = (tid & 3) * 8;         // staging col offset (elems)
  const u16* Ag  = A + (size_t)(m0 + sr) * K + so;
  const u16* Ag2 = A + (size_t)(m0 + sr + 64) * K + so;
  const u16* Bg  = B + (size_t)(n0 + sr) * K + so;
  const u16* Bg2 = B + (size_t)(n0 + sr + 64) * K + so;
  u16* Aw  = &Al[sr * 40 + so];
  u16* Aw2 = &Al[(sr + 64) * 40 + so];
  u16* Bw  = &Bl[sr * 40 + so];
  u16* Bw2 = &Bl[(sr + 64) * 40 + so];
  const u16* af = &Al[(wm * 64 + lr) * 40 + lg * 8];
  const u16* bp = &Bl[(wn * 64 + lr) * 40 + lg * 8];

  for (int k0 = 0; k0 < K; k0 += 32) {
    if (k0) __syncthreads();
    *(uint4*)Aw  = *(const uint4*)(Ag + k0);
    *(uint4*)Aw2 = *(const uint4*)(Ag2 + k0);
    *(uint4*)Bw  = *(const uint4*)(Bg + k0);
    *(uint4*)Bw2 = *(const uint4*)(Bg2 + k0);
    __syncthreads();
    bf16x8 a[4], b[4];
#pragma unroll
    for (int m = 0; m < 4; m++) a[m] = *(const bf16x8*)(af + m * 16 * 40);
#pragma unroll
    for (int n = 0; n < 4; n++) b[n] = *(const bf16x8*)(bp + n * 16 * 40);
#pragma unroll
    for (int m = 0; m < 4; m++)
#pragma unroll
      for (int n = 0; n < 4; n++)
        acc[m][n] = __builtin_amdgcn_mfma_f32_16x16x32_bf16(a[m], b[n], acc[m][n], 0, 0, 0);
  }

#pragma unroll
  for (int m = 0; m < 4; m++) {
    const int row = m0 + wm * 64 + m * 16 + lg * 4;
#pragma unroll
    for (int n = 0; n < 4; n++) {
      const int col = n0 + wn * 64 + n * 16 + lr;
      const float bs = bias[col];
#pragma unroll
      for (int r = 0; r < 4; r++)
        C[(size_t)(row + r) * N + col] = acc[m][n][r] + bs;
    }
  }
}

// ---------------- RMSNorm + interleaved RoPE for q,k; writes head-major bf16 ----------------
// grid.x * 4 waves = rows (s*24+h), grid.y: 0=q (scale folded), 1=k
__global__ __launch_bounds__(256) void k_norm_rope(
    const float* __restrict__ Qraw, const float* __restrict__ Kraw,
    const float* __restrict__ cosp, const float* __restrict__ sinp,
    const float* __restrict__ wq, const float* __restrict__ wk,
    u16* __restrict__ Qh, u16* __restrict__ Kh)
{
  const int isK = blockIdx.y;
  const float* __restrict__ src = isK ? Kraw : Qraw;
  const float* __restrict__ wgt = isK ? wk : wq;
  u16* __restrict__ dst = isK ? Kh : Qh;
  const float scl = isK ? 1.0f : 0.08838834764831845f;  // 1/sqrt(128) folded into q
  const int w4 = threadIdx.x >> 6, l = threadIdx.x & 63;
  const int row = blockIdx.x * 4 + w4;
  const int s = row / 24, h = row - s * 24;
  const float2 x = *(const float2*)&src[(size_t)s * HID + h * HD + 2 * l];
  float ss = x.x * x.x + x.y * x.y;
#pragma unroll
  for (int off = 32; off; off >>= 1) ss += __shfl_xor(ss, off);
  const float rn = rsqrtf(ss * (1.0f / 128.0f) + 1e-6f);
  const float w0 = wgt[2 * l], w1 = wgt[2 * l + 1];
  const float c0 = cosp[s * HD + 2 * l], c1 = cosp[s * HD + 2 * l + 1];
  const float s0 = sinp[s * HD + 2 * l], s1 = sinp[s * HD + 2 * l + 1];
  const float y0 = x.x * rn * w0, y1 = x.y * rn * w1;
  const float o0 = (y0 * c0 - y1 * s0) * scl;
  const float o1 = (y1 * c1 + y0 * s1) * scl;
  const uint32_t pk = (uint32_t)f2bf(o0) | ((uint32_t)f2bf(o1) << 16);
  *(uint32_t*)&dst[((size_t)h * S_LEN + s) * HD + 2 * l] = pk;
}

// ---------------- RMSNorm (no weight, eps 1e-5) for ip_k (->bf16 head-major) and ip_v (->f32) ----------------
__global__ __launch_bounds__(256) void k_ip_norm(
    const float* __restrict__ Kraw, const float* __restrict__ Vraw,
    u16* __restrict__ Kh, float* __restrict__ Vn)
{
  const int isV = blockIdx.y;
  const float* __restrict__ src = isV ? Vraw : Kraw;
  const int w4 = threadIdx.x >> 6, l = threadIdx.x & 63;
  const int row = blockIdx.x * 4 + w4;
  const int t = row / 24, h = row - t * 24;
  const float2 x = *(const float2*)&src[(size_t)t * HID + h * HD + 2 * l];
  float ss = x.x * x.x + x.y * x.y;
#pragma unroll
  for (int off = 32; off; off >>= 1) ss += __shfl_xor(ss, off);
  const float rn = rsqrtf(ss * (1.0f / 128.0f) + 1e-5f);
  const float o0 = x.x * rn, o1 = x.y * rn;
  if (isV) {
    *(float2*)&Vn[(size_t)t * HID + h * HD + 2 * l] = make_float2(o0, o1);
  } else {
    const uint32_t pk = (uint32_t)f2bf(o0) | ((uint32_t)f2bf(o1) << 16);
    *(uint32_t*)&Kh[((size_t)h * 128 + t) * HD + 2 * l] = pk;
  }
}

// ---------------- transpose f32 [S][3072] per-head -> bf16 [24][128][S] ----------------
__global__ __launch_bounds__(256) void k_transpose(
    const float* __restrict__ X, u16* __restrict__ Y, int S)
{
  const int h = blockIdx.z, d0 = blockIdx.y * 32, s0 = blockIdx.x * 32;
  __shared__ float tile[32][33];
  const int c = threadIdx.x & 31, rb = threadIdx.x >> 5;
#pragma unroll
  for (int i = 0; i < 4; i++) {
    const int r = rb + i * 8;
    tile[r][c] = X[(size_t)(s0 + r) * HID + h * HD + d0 + c];
  }
  __syncthreads();
#pragma unroll
  for (int i = 0; i < 4; i++) {
    const int r = rb + i * 8;  // d-local
    Y[((size_t)h * HD + d0 + r) * S + s0 + c] = f2bf(tile[c][r]);
  }
}

// ---------------- flash attention ----------------
// Q: [24][2048][128] bf16 (pre-scaled), K: [24][kv][128] bf16, Vt: [24][128][kv] bf16
// Out: [2048][3072] f32. block = 256 (4 waves x 16 q-rows), KV tile = 64.
__global__ __launch_bounds__(256) void k_attn(
    const u16* __restrict__ Q, const u16* __restrict__ K, const u16* __restrict__ Vt,
    float* __restrict__ Out, int kv_len, int add)
{
  const int h = blockIdx.y;
  const int q0 = blockIdx.x * 64;
  const int tid = threadIdx.x, w = tid >> 6, l = tid & 63;
  const int lr = l & 15, lg = l >> 4;

  __shared__ u16 Kl[64][136];   // 272B stride: 16B aligned, 2-way banks
  __shared__ u16 Vl[128][88];   // 176B stride: 16B aligned, 2-way banks
  __shared__ u16 Pl[4][16][88]; // per-wave P tile

  bf16x8 qf[4];
  {
    const u16* qp = &Q[((size_t)h * S_LEN + q0 + w * 16 + lr) * HD];
#pragma unroll
    for (int db = 0; db < 4; db++) qf[db] = *(const bf16x8*)&qp[db * 32 + lg * 8];
  }

  float m_[4], ls[4];
  f32x4 acc[8];
#pragma unroll
  for (int r = 0; r < 4; r++) { m_[r] = -1e30f; ls[r] = 0.f; }
#pragma unroll
  for (int nb = 0; nb < 8; nb++) acc[nb] = f32x4{0.f, 0.f, 0.f, 0.f};

  for (int kv0 = 0; kv0 < kv_len; kv0 += 64) {
#pragma unroll
    for (int i = 0; i < 4; i++) {
      const int c = tid + i * 256;
      { const int r = c >> 4, o = (c & 15) * 8;
        *(uint4*)&Kl[r][o] = *(const uint4*)&K[((size_t)h * kv_len + kv0 + r) * HD + o]; }
      { const int r = c >> 3, o = (c & 7) * 8;
        *(uint4*)&Vl[r][o] = *(const uint4*)&Vt[((size_t)h * HD + r) * kv_len + kv0 + o]; }
    }
    __syncthreads();

    f32x4 sf[4];
#pragma unroll
    for (int kb = 0; kb < 4; kb++) {
      f32x4 s = f32x4{0.f, 0.f, 0.f, 0.f};
#pragma unroll
      for (int db = 0; db < 4; db++) {
        bf16x8 b = *(const bf16x8*)&Kl[kb * 16 + lr][db * 32 + lg * 8];
        s = __builtin_amdgcn_mfma_f32_16x16x32_bf16(qf[db], b, s, 0, 0, 0);
      }
      sf[kb] = s;
    }

    float pv[4][4], rescv[4];
#pragma unroll
    for (int r = 0; r < 4; r++) {
      float tm = fmaxf(fmaxf(sf[0][r], sf[1][r]), fmaxf(sf[2][r], sf[3][r]));
#pragma unroll
      for (int off = 8; off; off >>= 1) tm = fmaxf(tm, __shfl_xor(tm, off));
      const float mn = fmaxf(m_[r], tm);
      const float resc = __expf(m_[r] - mn);
      float ps = 0.f;
#pragma unroll
      for (int kb = 0; kb < 4; kb++) { const float p = __expf(sf[kb][r] - mn); pv[kb][r] = p; ps += p; }
#pragma unroll
      for (int off = 8; off; off >>= 1) ps += __shfl_xor(ps, off);
      ls[r] = ls[r] * resc + ps;
      m_[r] = mn; rescv[r] = resc;
    }
#pragma unroll
    for (int nb = 0; nb < 8; nb++)
#pragma unroll
      for (int r = 0; r < 4; r++) acc[nb][r] *= rescv[r];

#pragma unroll
    for (int kb = 0; kb < 4; kb++)
#pragma unroll
      for (int r = 0; r < 4; r++)
        Pl[w][lg * 4 + r][kb * 16 + lr] = f2bf(pv[kb][r]);

    __syncthreads();  // safety: P store -> P read (also covers cross-wave LDS quiesce)

    // PV: contraction over the 64-wide KV tile = 2 MFMA k-steps of 32 (FIX: was 4 -> OOB)
#pragma unroll
    for (int kb = 0; kb < 2; kb++) {
      bf16x8 a = *(const bf16x8*)&Pl[w][lr][kb * 32 + lg * 8];
#pragma unroll
      for (int nb = 0; nb < 8; nb++) {
        bf16x8 b = *(const bf16x8*)&Vl[nb * 16 + lr][kb * 32 + lg * 8];
        acc[nb] = __builtin_amdgcn_mfma_f32_16x16x32_bf16(a, b, acc[nb], 0, 0, 0);
      }
    }
    __syncthreads();
  }

  float inv[4];
#pragma unroll
  for (int r = 0; r < 4; r++) inv[r] = 1.0f / ls[r];
#pragma unroll
  for (int nb = 0; nb < 8; nb++)
#pragma unroll
    for (int r = 0; r < 4; r++) {
      const int row = q0 + w * 16 + lg * 4 + r;
      const int col = h * HD + nb * 16 + lr;
      const size_t idx = (size_t)row * HID + col;
      const float v = acc[nb][r] * inv[r];
      if (add) Out[idx] += v; else Out[idx] = v;
    }
}

// ---------------- launcher ----------------
extern "C" void kernel_launch(void* const* d_in, const int* in_sizes, int n_in,
                              void* d_out, int out_size, void* d_ws, size_t ws_size,
                              hipStream_t stream) {
  const float* hs   = (const float*)d_in[0];
  const float* cosp = (const float*)d_in[1];
  const float* sinp = (const float*)d_in[2];
  const float* iph  = (const float*)d_in[3];
  const float* Wq   = (const float*)d_in[4];
  const float* bq   = (const float*)d_in[5];
  const float* Wk   = (const float*)d_in[6];
  const float* bk   = (const float*)d_in[7];
  const float* Wv   = (const float*)d_in[8];
  const float* bv   = (const float*)d_in[9];
  const float* nqw  = (const float*)d_in[10];
  const float* nkw  = (const float*)d_in[11];
  const float* Wkip = (const float*)d_in[12];
  const float* Wvip = (const float*)d_in[13];
  float* out = (float*)d_out;

  uint8_t* base = (uint8_t*)d_ws;
  size_t off = 0;
  auto alloc = [&](size_t bytes) { uint8_t* p = base + off; off += (bytes + 255) & ~(size_t)255; return p; };

  u16* X16 = (u16*)alloc(2048ull * 3072 * 2);
  uint8_t* regionB = base + off;               // weights region, reused later
  u16* W16q  = (u16*)alloc(3072ull * 3072 * 2);
  u16* W16k  = (u16*)alloc(3072ull * 3072 * 2);
  u16* W16v  = (u16*)alloc(3072ull * 3072 * 2);
  u16* Wip16k = (u16*)alloc(3072ull * 4096 * 2);
  u16* Wip16v = (u16*)alloc(3072ull * 4096 * 2);
  u16* ip16   = (u16*)alloc(128ull * 4096 * 2);
  float* Qraw = (float*)alloc(2048ull * 3072 * 4);
  float* Kraw = (float*)alloc(2048ull * 3072 * 4);
  float* Vraw = (float*)alloc(2048ull * 3072 * 4);
  float* ipKraw = (float*)alloc(128ull * 3072 * 4);
  float* ipVraw = (float*)alloc(128ull * 3072 * 4);

  // region D aliases regionB (weights dead after GEMMs; stream-ordered)
  uint8_t* dp = regionB;
  auto allocD = [&](size_t bytes) { uint8_t* p = dp; dp += (bytes + 255) & ~(size_t)255; return p; };
  u16* Qh   = (u16*)allocD(24ull * 2048 * 128 * 2);
  u16* Kh   = (u16*)allocD(24ull * 2048 * 128 * 2);
  u16* Vt   = (u16*)allocD(24ull * 128 * 2048 * 2);
  u16* ipKh = (u16*)allocD(24ull * 128 * 128 * 2);
  u16* ipVt = (u16*)allocD(24ull * 128 * 128 * 2);
  float* ipVn = (float*)allocD(128ull * 3072 * 4);

  // 1. convert to bf16
  k_f2bf<<<6144, 256, 0, stream>>>(hs, X16, 1572864);
  k_f2bf<<<9216, 256, 0, stream>>>(Wq, W16q, 2359296);
  k_f2bf<<<9216, 256, 0, stream>>>(Wk, W16k, 2359296);
  k_f2bf<<<9216, 256, 0, stream>>>(Wv, W16v, 2359296);
  k_f2bf<<<12288, 256, 0, stream>>>(Wkip, Wip16k, 3145728);
  k_f2bf<<<12288, 256, 0, stream>>>(Wvip, Wip16v, 3145728);
  k_f2bf<<<512, 256, 0, stream>>>(iph, ip16, 131072);

  // 2. projections
  k_gemm_bt<<<dim3(16, 24, 3), 256, 0, stream>>>(X16, W16q, W16k, W16v, bq, bk, bv,
                                                 Qraw, Kraw, Vraw, 2048, 3072, 3072);
  k_gemm_bt<<<dim3(1, 24, 2), 256, 0, stream>>>(ip16, Wip16k, Wip16v, Wip16v, bq, bq, bq,
                                                ipKraw, ipVraw, ipVraw, 128, 3072, 4096);

  // 3. norms / rope / transposes
  k_norm_rope<<<dim3(12288, 2), 256, 0, stream>>>(Qraw, Kraw, cosp, sinp, nqw, nkw, Qh, Kh);
  k_ip_norm<<<dim3(768, 2), 256, 0, stream>>>(ipKraw, ipVraw, ipKh, ipVn);
  k_transpose<<<dim3(64, 4, 24), 256, 0, stream>>>(Vraw, Vt, 2048);
  k_transpose<<<dim3(4, 4, 24), 256, 0, stream>>>(ipVn, ipVt, 128);

  // 4. attentions (attn2 accumulates)
  k_attn<<<dim3(32, 24), 256, 0, stream>>>(Qh, Kh, Vt, out, 2048, 0);
  k_attn<<<dim3(32, 24), 256, 0, stream>>>(Qh, ipKh, ipVt, out, 128, 1);
}

// Round 5
// 687.154 us; speedup vs baseline: 1.0576x; 1.0576x over previous
//
#include <hip/hip_runtime.h>
#include <stdint.h>

typedef unsigned short u16;
typedef __bf16 bf16x8 __attribute__((ext_vector_type(8)));
typedef float f32x4 __attribute__((ext_vector_type(4)));

#define HEADS 24
#define HD 128
#define S_LEN 2048
#define HID 3072

__device__ __forceinline__ u16 f2bf(float f) {
  union { float f; uint32_t u; } a; a.f = f;
  return (u16)((a.u + 0x7FFFu + ((a.u >> 16) & 1u)) >> 16);
}

// async global->LDS, 16B per lane. lds must be wave-uniform; HW writes lane i at lds + i*16.
__device__ __forceinline__ void gload16(const u16* g, u16* lds) {
  __builtin_amdgcn_global_load_lds(
      (const __attribute__((address_space(1))) void*)g,
      (__attribute__((address_space(3))) void*)lds, 16, 0, 0);
}

// ---------------- f32 -> bf16 convert (vectorized) ----------------
__global__ __launch_bounds__(256) void k_f2bf(const float* __restrict__ in,
                                              u16* __restrict__ out, int n4) {
  int i = blockIdx.x * 256 + threadIdx.x;
  if (i >= n4) return;
  float4 v = ((const float4*)in)[i];
  uint2 pk;
  pk.x = (uint32_t)f2bf(v.x) | ((uint32_t)f2bf(v.y) << 16);
  pk.y = (uint32_t)f2bf(v.z) | ((uint32_t)f2bf(v.w) << 16);
  ((uint2*)out)[i] = pk;
}

// ---------------- bf16 GEMM  C[m][n] = sum_k A[m][k]*B[n][k] (+ bias[n]) ----------------
// m97 structure: 128x128 tile, BK=32, global_load_lds w16, linear LDS, 2 barriers/step.
// 256 threads = 4 waves (2x2), each wave 64x64 (4x4 frags of 16x16x32).
// atomic_split==0: blockIdx.x = m-tile, full K, bias added, plain store.
// atomic_split> 0: m0=0, K-chunk = [bx*atomic_split, +atomic_split), atomicAdd, no bias.
__global__ __launch_bounds__(256) void k_gemm_bt(
    const u16* __restrict__ A,
    const u16* __restrict__ B0, const u16* __restrict__ B1, const u16* __restrict__ B2,
    const float* __restrict__ bias0, const float* __restrict__ bias1, const float* __restrict__ bias2,
    float* __restrict__ C0, float* __restrict__ C1, float* __restrict__ C2,
    int N, int K, int atomic_split)
{
  const int z = blockIdx.z;
  const u16* __restrict__ B = (z == 0) ? B0 : (z == 1 ? B1 : B2);
  const float* __restrict__ bias = (z == 0) ? bias0 : (z == 1 ? bias1 : bias2);
  float* __restrict__ C = (z == 0) ? C0 : (z == 1 ? C1 : C2);
  const int m0 = atomic_split ? 0 : blockIdx.x * 128;
  const int n0 = blockIdx.y * 128;
  const int kb = atomic_split ? blockIdx.x * atomic_split : 0;
  const int ke = atomic_split ? kb + atomic_split : K;
  const int tid = threadIdx.x, l = tid & 63, w = tid >> 6;
  const int wm = w >> 1, wn = w & 1;
  const int lr = l & 15, lg = l >> 4;

  __shared__ u16 Al[128 * 32];  // linear: row-major [128][32], 64B rows (gload_lds needs linear)
  __shared__ u16 Bl[128 * 32];

  f32x4 acc[4][4];
#pragma unroll
  for (int m = 0; m < 4; m++)
#pragma unroll
    for (int n = 0; n < 4; n++) acc[m][n] = f32x4{0.f, 0.f, 0.f, 0.f};

  // staging geometry: 8 chunks of 1KB (16 rows each); chunk c = j*4 + w.
  // lane l covers row c*16 + (l>>2), col 16B-slot (l&3).
  const int srow = l >> 2, scol = (l & 3) * 8;
  const u16* Ab = A + (size_t)(m0 + srow) * K + scol;
  const u16* Bb = B + (size_t)(n0 + srow) * K + scol;
  const u16* af = &Al[(wm * 64 + lr) * 32 + lg * 8];
  const u16* bf = &Bl[(wn * 64 + lr) * 32 + lg * 8];

  for (int k0 = kb; k0 < ke; k0 += 32) {
    if (k0 != kb) __syncthreads();
#pragma unroll
    for (int j = 0; j < 2; j++) {
      const int c = j * 4 + w;
      gload16(Ab + (size_t)c * 16 * K + k0, &Al[c * 512]);
      gload16(Bb + (size_t)c * 16 * K + k0, &Bl[c * 512]);
    }
    __syncthreads();
    bf16x8 a[4], b[4];
#pragma unroll
    for (int m = 0; m < 4; m++) a[m] = *(const bf16x8*)(af + m * 16 * 32);
#pragma unroll
    for (int n = 0; n < 4; n++) b[n] = *(const bf16x8*)(bf + n * 16 * 32);
#pragma unroll
    for (int m = 0; m < 4; m++)
#pragma unroll
      for (int n = 0; n < 4; n++)
        acc[m][n] = __builtin_amdgcn_mfma_f32_16x16x32_bf16(a[m], b[n], acc[m][n], 0, 0, 0);
  }

  if (atomic_split) {
#pragma unroll
    for (int m = 0; m < 4; m++) {
      const int row = m0 + wm * 64 + m * 16 + lg * 4;
#pragma unroll
      for (int n = 0; n < 4; n++) {
        const int col = n0 + wn * 64 + n * 16 + lr;
#pragma unroll
        for (int r = 0; r < 4; r++)
          atomicAdd(&C[(size_t)(row + r) * N + col], acc[m][n][r]);
      }
    }
  } else {
#pragma unroll
    for (int m = 0; m < 4; m++) {
      const int row = m0 + wm * 64 + m * 16 + lg * 4;
#pragma unroll
      for (int n = 0; n < 4; n++) {
        const int col = n0 + wn * 64 + n * 16 + lr;
        const float bs = bias[col];
#pragma unroll
        for (int r = 0; r < 4; r++)
          C[(size_t)(row + r) * N + col] = acc[m][n][r] + bs;
      }
    }
  }
}

// ---------------- RMSNorm + interleaved RoPE for q,k; writes head-major bf16 ----------------
__global__ __launch_bounds__(256) void k_norm_rope(
    const float* __restrict__ Qraw, const float* __restrict__ Kraw,
    const float* __restrict__ cosp, const float* __restrict__ sinp,
    const float* __restrict__ wq, const float* __restrict__ wk,
    u16* __restrict__ Qh, u16* __restrict__ Kh)
{
  const int isK = blockIdx.y;
  const float* __restrict__ src = isK ? Kraw : Qraw;
  const float* __restrict__ wgt = isK ? wk : wq;
  u16* __restrict__ dst = isK ? Kh : Qh;
  const float scl = isK ? 1.0f : 0.08838834764831845f;  // 1/sqrt(128) folded into q
  const int w4 = threadIdx.x >> 6, l = threadIdx.x & 63;
  const int row = blockIdx.x * 4 + w4;
  const int s = row / 24, h = row - s * 24;
  const float2 x = *(const float2*)&src[(size_t)s * HID + h * HD + 2 * l];
  float ss = x.x * x.x + x.y * x.y;
#pragma unroll
  for (int off = 32; off; off >>= 1) ss += __shfl_xor(ss, off);
  const float rn = rsqrtf(ss * (1.0f / 128.0f) + 1e-6f);
  const float w0 = wgt[2 * l], w1 = wgt[2 * l + 1];
  const float c0 = cosp[s * HD + 2 * l], c1 = cosp[s * HD + 2 * l + 1];
  const float s0 = sinp[s * HD + 2 * l], s1 = sinp[s * HD + 2 * l + 1];
  const float y0 = x.x * rn * w0, y1 = x.y * rn * w1;
  const float o0 = (y0 * c0 - y1 * s0) * scl;
  const float o1 = (y1 * c1 + y0 * s1) * scl;
  const uint32_t pk = (uint32_t)f2bf(o0) | ((uint32_t)f2bf(o1) << 16);
  *(uint32_t*)&dst[((size_t)h * S_LEN + s) * HD + 2 * l] = pk;
}

// ---------------- RMSNorm (no weight, eps 1e-5) for ip_k (->bf16 head-major) and ip_v (->f32) ----------------
__global__ __launch_bounds__(256) void k_ip_norm(
    const float* __restrict__ Kraw, const float* __restrict__ Vraw,
    u16* __restrict__ Kh, float* __restrict__ Vn)
{
  const int isV = blockIdx.y;
  const float* __restrict__ src = isV ? Vraw : Kraw;
  const int w4 = threadIdx.x >> 6, l = threadIdx.x & 63;
  const int row = blockIdx.x * 4 + w4;
  const int t = row / 24, h = row - t * 24;
  const float2 x = *(const float2*)&src[(size_t)t * HID + h * HD + 2 * l];
  float ss = x.x * x.x + x.y * x.y;
#pragma unroll
  for (int off = 32; off; off >>= 1) ss += __shfl_xor(ss, off);
  const float rn = rsqrtf(ss * (1.0f / 128.0f) + 1e-5f);
  const float o0 = x.x * rn, o1 = x.y * rn;
  if (isV) {
    *(float2*)&Vn[(size_t)t * HID + h * HD + 2 * l] = make_float2(o0, o1);
  } else {
    const uint32_t pk = (uint32_t)f2bf(o0) | ((uint32_t)f2bf(o1) << 16);
    *(uint32_t*)&Kh[((size_t)h * 128 + t) * HD + 2 * l] = pk;
  }
}

// ---------------- transpose f32 [S][3072] per-head -> bf16 [24][128][S] ----------------
__global__ __launch_bounds__(256) void k_transpose(
    const float* __restrict__ X, u16* __restrict__ Y, int S)
{
  const int h = blockIdx.z, d0 = blockIdx.y * 32, s0 = blockIdx.x * 32;
  __shared__ float tile[32][33];
  const int c = threadIdx.x & 31, rb = threadIdx.x >> 5;
#pragma unroll
  for (int i = 0; i < 4; i++) {
    const int r = rb + i * 8;
    tile[r][c] = X[(size_t)(s0 + r) * HID + h * HD + d0 + c];
  }
  __syncthreads();
#pragma unroll
  for (int i = 0; i < 4; i++) {
    const int r = rb + i * 8;  // d-local
    Y[((size_t)h * HD + d0 + r) * S + s0 + c] = f2bf(tile[c][r]);
  }
}

// ---------------- flash attention ----------------
// Q: [24][2048][128] bf16 (pre-scaled), K: [24][kv][128] bf16, Vt: [24][128][kv] bf16
// Out: [2048][3072] f32. block = 256 (4 waves x 16 q-rows), KV tile = 64.
__global__ __launch_bounds__(256) void k_attn(
    const u16* __restrict__ Q, const u16* __restrict__ K, const u16* __restrict__ Vt,
    float* __restrict__ Out, int kv_len, int add)
{
  const int h = blockIdx.y;
  const int q0 = blockIdx.x * 64;
  const int tid = threadIdx.x, w = tid >> 6, l = tid & 63;
  const int lr = l & 15, lg = l >> 4;

  __shared__ u16 Kl[64][136];   // 272B stride: 16B aligned, 2-way banks
  __shared__ u16 Vl[128][88];   // 176B stride: 16B aligned, 2-way banks
  __shared__ u16 Pl[4][16][88]; // per-wave P tile

  bf16x8 qf[4];
  {
    const u16* qp = &Q[((size_t)h * S_LEN + q0 + w * 16 + lr) * HD];
#pragma unroll
    for (int db = 0; db < 4; db++) qf[db] = *(const bf16x8*)&qp[db * 32 + lg * 8];
  }

  float m_[4], ls[4];
  f32x4 acc[8];
#pragma unroll
  for (int r = 0; r < 4; r++) { m_[r] = -1e30f; ls[r] = 0.f; }
#pragma unroll
  for (int nb = 0; nb < 8; nb++) acc[nb] = f32x4{0.f, 0.f, 0.f, 0.f};

  for (int kv0 = 0; kv0 < kv_len; kv0 += 64) {
#pragma unroll
    for (int i = 0; i < 4; i++) {
      const int c = tid + i * 256;
      { const int r = c >> 4, o = (c & 15) * 8;
        *(uint4*)&Kl[r][o] = *(const uint4*)&K[((size_t)h * kv_len + kv0 + r) * HD + o]; }
      { const int r = c >> 3, o = (c & 7) * 8;
        *(uint4*)&Vl[r][o] = *(const uint4*)&Vt[((size_t)h * HD + r) * kv_len + kv0 + o]; }
    }
    __syncthreads();

    f32x4 sf[4];
#pragma unroll
    for (int kb = 0; kb < 4; kb++) {
      f32x4 s = f32x4{0.f, 0.f, 0.f, 0.f};
#pragma unroll
      for (int db = 0; db < 4; db++) {
        bf16x8 b = *(const bf16x8*)&Kl[kb * 16 + lr][db * 32 + lg * 8];
        s = __builtin_amdgcn_mfma_f32_16x16x32_bf16(qf[db], b, s, 0, 0, 0);
      }
      sf[kb] = s;
    }

    float pv[4][4], rescv[4];
#pragma unroll
    for (int r = 0; r < 4; r++) {
      float tm = fmaxf(fmaxf(sf[0][r], sf[1][r]), fmaxf(sf[2][r], sf[3][r]));
#pragma unroll
      for (int off = 8; off; off >>= 1) tm = fmaxf(tm, __shfl_xor(tm, off));
      const float mn = fmaxf(m_[r], tm);
      const float resc = __expf(m_[r] - mn);
      float ps = 0.f;
#pragma unroll
      for (int kb = 0; kb < 4; kb++) { const float p = __expf(sf[kb][r] - mn); pv[kb][r] = p; ps += p; }
#pragma unroll
      for (int off = 8; off; off >>= 1) ps += __shfl_xor(ps, off);
      ls[r] = ls[r] * resc + ps;
      m_[r] = mn; rescv[r] = resc;
    }
#pragma unroll
    for (int nb = 0; nb < 8; nb++)
#pragma unroll
      for (int r = 0; r < 4; r++) acc[nb][r] *= rescv[r];

#pragma unroll
    for (int kb = 0; kb < 4; kb++)
#pragma unroll
      for (int r = 0; r < 4; r++)
        Pl[w][lg * 4 + r][kb * 16 + lr] = f2bf(pv[kb][r]);

    // no barrier needed: Pl[w] is per-wave (same-wave DS ordering), Vl was fenced above.

    // PV: contraction over the 64-wide KV tile = 2 MFMA k-steps of 32
#pragma unroll
    for (int kb = 0; kb < 2; kb++) {
      bf16x8 a = *(const bf16x8*)&Pl[w][lr][kb * 32 + lg * 8];
#pragma unroll
      for (int nb = 0; nb < 8; nb++) {
        bf16x8 b = *(const bf16x8*)&Vl[nb * 16 + lr][kb * 32 + lg * 8];
        acc[nb] = __builtin_amdgcn_mfma_f32_16x16x32_bf16(a, b, acc[nb], 0, 0, 0);
      }
    }
    __syncthreads();
  }

  float inv[4];
#pragma unroll
  for (int r = 0; r < 4; r++) inv[r] = 1.0f / ls[r];
#pragma unroll
  for (int nb = 0; nb < 8; nb++)
#pragma unroll
    for (int r = 0; r < 4; r++) {
      const int row = q0 + w * 16 + lg * 4 + r;
      const int col = h * HD + nb * 16 + lr;
      const size_t idx = (size_t)row * HID + col;
      const float v = acc[nb][r] * inv[r];
      if (add) Out[idx] += v; else Out[idx] = v;
    }
}

// ---------------- launcher ----------------
extern "C" void kernel_launch(void* const* d_in, const int* in_sizes, int n_in,
                              void* d_out, int out_size, void* d_ws, size_t ws_size,
                              hipStream_t stream) {
  const float* hs   = (const float*)d_in[0];
  const float* cosp = (const float*)d_in[1];
  const float* sinp = (const float*)d_in[2];
  const float* iph  = (const float*)d_in[3];
  const float* Wq   = (const float*)d_in[4];
  const float* bq   = (const float*)d_in[5];
  const float* Wk   = (const float*)d_in[6];
  const float* bk   = (const float*)d_in[7];
  const float* Wv   = (const float*)d_in[8];
  const float* bv   = (const float*)d_in[9];
  const float* nqw  = (const float*)d_in[10];
  const float* nkw  = (const float*)d_in[11];
  const float* Wkip = (const float*)d_in[12];
  const float* Wvip = (const float*)d_in[13];
  float* out = (float*)d_out;

  uint8_t* base = (uint8_t*)d_ws;
  size_t off = 0;
  auto alloc = [&](size_t bytes) { uint8_t* p = base + off; off += (bytes + 255) & ~(size_t)255; return p; };

  u16* X16 = (u16*)alloc(2048ull * 3072 * 2);
  uint8_t* regionB = base + off;               // weights region, reused later
  u16* W16q  = (u16*)alloc(3072ull * 3072 * 2);
  u16* W16k  = (u16*)alloc(3072ull * 3072 * 2);
  u16* W16v  = (u16*)alloc(3072ull * 3072 * 2);
  u16* Wip16k = (u16*)alloc(3072ull * 4096 * 2);
  u16* Wip16v = (u16*)alloc(3072ull * 4096 * 2);
  u16* ip16   = (u16*)alloc(128ull * 4096 * 2);
  float* Qraw = (float*)alloc(2048ull * 3072 * 4);
  float* Kraw = (float*)alloc(2048ull * 3072 * 4);
  float* Vraw = (float*)alloc(2048ull * 3072 * 4);
  float* ipKraw = (float*)alloc(128ull * 3072 * 4);
  float* ipVraw = (float*)alloc(128ull * 3072 * 4);

  // region D aliases regionB (weights dead after GEMMs; stream-ordered)
  uint8_t* dp = regionB;
  auto allocD = [&](size_t bytes) { uint8_t* p = dp; dp += (bytes + 255) & ~(size_t)255; return p; };
  u16* Qh   = (u16*)allocD(24ull * 2048 * 128 * 2);
  u16* Kh   = (u16*)allocD(24ull * 2048 * 128 * 2);
  u16* Vt   = (u16*)allocD(24ull * 128 * 2048 * 2);
  u16* ipKh = (u16*)allocD(24ull * 128 * 128 * 2);
  u16* ipVt = (u16*)allocD(24ull * 128 * 128 * 2);
  float* ipVn = (float*)allocD(128ull * 3072 * 4);

  // 1. convert to bf16
  k_f2bf<<<6144, 256, 0, stream>>>(hs, X16, 1572864);
  k_f2bf<<<9216, 256, 0, stream>>>(Wq, W16q, 2359296);
  k_f2bf<<<9216, 256, 0, stream>>>(Wk, W16k, 2359296);
  k_f2bf<<<9216, 256, 0, stream>>>(Wv, W16v, 2359296);
  k_f2bf<<<12288, 256, 0, stream>>>(Wkip, Wip16k, 3145728);
  k_f2bf<<<12288, 256, 0, stream>>>(Wvip, Wip16v, 3145728);
  k_f2bf<<<512, 256, 0, stream>>>(iph, ip16, 131072);

  // zero split-K accumulators (ws is re-poisoned 0xAA before every call)
  hipMemsetAsync(ipKraw, 0, 128ull * 3072 * 4, stream);
  hipMemsetAsync(ipVraw, 0, 128ull * 3072 * 4, stream);

  // 2. projections
  k_gemm_bt<<<dim3(16, 24, 3), 256, 0, stream>>>(X16, W16q, W16k, W16v, bq, bk, bv,
                                                 Qraw, Kraw, Vraw, 3072, 3072, 0);
  k_gemm_bt<<<dim3(4, 24, 2), 256, 0, stream>>>(ip16, Wip16k, Wip16v, Wip16v, bq, bq, bq,
                                                ipKraw, ipVraw, ipVraw, 3072, 4096, 1024);

  // 3. norms / rope / transposes
  k_norm_rope<<<dim3(12288, 2), 256, 0, stream>>>(Qraw, Kraw, cosp, sinp, nqw, nkw, Qh, Kh);
  k_ip_norm<<<dim3(768, 2), 256, 0, stream>>>(ipKraw, ipVraw, ipKh, ipVn);
  k_transpose<<<dim3(64, 4, 24), 256, 0, stream>>>(Vraw, Vt, 2048);
  k_transpose<<<dim3(4, 4, 24), 256, 0, stream>>>(ipVn, ipVt, 128);

  // 4. attentions (attn2 accumulates)
  k_attn<<<dim3(32, 24), 256, 0, stream>>>(Qh, Kh, Vt, out, 2048, 0);
  k_attn<<<dim3(32, 24), 256, 0, stream>>>(Qh, ipKh, ipVt, out, 128, 1);
}

// Round 8
// 650.619 us; speedup vs baseline: 1.1169x; 1.0562x over previous
//
#include <hip/hip_runtime.h>
#include <stdint.h>

typedef unsigned short u16;
typedef __bf16 bf16x8 __attribute__((ext_vector_type(8)));
typedef float f32x4 __attribute__((ext_vector_type(4)));

#define HEADS 24
#define HD 128
#define S_LEN 2048
#define HID 3072

__device__ __forceinline__ u16 f2bf(float f) {
  union { float f; uint32_t u; } a; a.f = f;
  return (u16)((a.u + 0x7FFFu + ((a.u >> 16) & 1u)) >> 16);
}

// async global->LDS, 16B per lane. lds must be wave-uniform; HW writes lane i at lds + i*16.
__device__ __forceinline__ void gload16(const u16* g, u16* lds) {
  __builtin_amdgcn_global_load_lds(
      (const __attribute__((address_space(1))) void*)g,
      (__attribute__((address_space(3))) void*)lds, 16, 0, 0);
}

// ---------------- fused f32->bf16 converts + zero-fills (one dispatch) ----------------
struct ConvSeg { const float* in; void* out; int n4; int mode; };  // mode 0: cvt, 1: zero f32x4
struct ConvArgs { ConvSeg s[9]; };

__global__ __launch_bounds__(256) void k_convert_all(ConvArgs a) {
  const int gid = blockIdx.x * 256 + threadIdx.x;
  const int stride = gridDim.x * 256;
#pragma unroll
  for (int sg = 0; sg < 9; sg++) {
    const int n = a.s[sg].n4;
    if (a.s[sg].mode == 0) {
      const float* __restrict__ in = a.s[sg].in;
      u16* __restrict__ out = (u16*)a.s[sg].out;
      for (int i = gid; i < n; i += stride) {
        float4 v = ((const float4*)in)[i];
        uint2 pk;
        pk.x = (uint32_t)f2bf(v.x) | ((uint32_t)f2bf(v.y) << 16);
        pk.y = (uint32_t)f2bf(v.z) | ((uint32_t)f2bf(v.w) << 16);
        ((uint2*)out)[i] = pk;
      }
    } else {
      float4* __restrict__ out = (float4*)a.s[sg].out;
      const float4 z = make_float4(0.f, 0.f, 0.f, 0.f);
      for (int i = gid; i < n; i += stride) out[i] = z;
    }
  }
}

// ---------------- bf16 GEMM  C[m][n] = sum_k A[m][k]*B[n][k] (+ bias[n]) ----------------
// m97 structure + XCD-aware bijective swizzle (requires nwg % 8 == 0).
__global__ __launch_bounds__(256) void k_gemm_bt(
    const u16* __restrict__ A,
    const u16* __restrict__ B0, const u16* __restrict__ B1, const u16* __restrict__ B2,
    const float* __restrict__ bias0, const float* __restrict__ bias1, const float* __restrict__ bias2,
    float* __restrict__ C0, float* __restrict__ C1, float* __restrict__ C2,
    int N, int K, int atomic_split)
{
  const int orig = blockIdx.x + gridDim.x * (blockIdx.y + gridDim.y * blockIdx.z);
  const int nwg = gridDim.x * gridDim.y * gridDim.z;
  const int cpx = nwg >> 3;
  const int wg = (orig & 7) * cpx + (orig >> 3);
  const int bx = wg % gridDim.x;
  const int rem = wg / gridDim.x;
  const int by = rem % gridDim.y;
  const int z = rem / gridDim.y;

  const u16* __restrict__ B = (z == 0) ? B0 : (z == 1 ? B1 : B2);
  const float* __restrict__ bias = (z == 0) ? bias0 : (z == 1 ? bias1 : bias2);
  float* __restrict__ C = (z == 0) ? C0 : (z == 1 ? C1 : C2);
  const int m0 = atomic_split ? 0 : bx * 128;
  const int n0 = by * 128;
  const int kb = atomic_split ? bx * atomic_split : 0;
  const int ke = atomic_split ? kb + atomic_split : K;
  const int tid = threadIdx.x, l = tid & 63, w = tid >> 6;
  const int wm = w >> 1, wn = w & 1;
  const int lr = l & 15, lg = l >> 4;

  __shared__ u16 Al[128 * 32];  // linear row-major [128][32] (gload_lds needs linear dest)
  __shared__ u16 Bl[128 * 32];

  f32x4 acc[4][4];
#pragma unroll
  for (int m = 0; m < 4; m++)
#pragma unroll
    for (int n = 0; n < 4; n++) acc[m][n] = f32x4{0.f, 0.f, 0.f, 0.f};

  const int srow = l >> 2, scol = (l & 3) * 8;
  const u16* Ab = A + (size_t)(m0 + srow) * K + scol;
  const u16* Bb = B + (size_t)(n0 + srow) * K + scol;
  const u16* af = &Al[(wm * 64 + lr) * 32 + lg * 8];
  const u16* bf = &Bl[(wn * 64 + lr) * 32 + lg * 8];

  for (int k0 = kb; k0 < ke; k0 += 32) {
    if (k0 != kb) __syncthreads();
#pragma unroll
    for (int j = 0; j < 2; j++) {
      const int c = j * 4 + w;
      gload16(Ab + (size_t)c * 16 * K + k0, &Al[c * 512]);
      gload16(Bb + (size_t)c * 16 * K + k0, &Bl[c * 512]);
    }
    __syncthreads();
    bf16x8 a[4], b[4];
#pragma unroll
    for (int m = 0; m < 4; m++) a[m] = *(const bf16x8*)(af + m * 16 * 32);
#pragma unroll
    for (int n = 0; n < 4; n++) b[n] = *(const bf16x8*)(bf + n * 16 * 32);
#pragma unroll
    for (int m = 0; m < 4; m++)
#pragma unroll
      for (int n = 0; n < 4; n++)
        acc[m][n] = __builtin_amdgcn_mfma_f32_16x16x32_bf16(a[m], b[n], acc[m][n], 0, 0, 0);
  }

  if (atomic_split) {
#pragma unroll
    for (int m = 0; m < 4; m++) {
      const int row = m0 + wm * 64 + m * 16 + lg * 4;
#pragma unroll
      for (int n = 0; n < 4; n++) {
        const int col = n0 + wn * 64 + n * 16 + lr;
#pragma unroll
        for (int r = 0; r < 4; r++)
          atomicAdd(&C[(size_t)(row + r) * N + col], acc[m][n][r]);
      }
    }
  } else {
#pragma unroll
    for (int m = 0; m < 4; m++) {
      const int row = m0 + wm * 64 + m * 16 + lg * 4;
#pragma unroll
      for (int n = 0; n < 4; n++) {
        const int col = n0 + wn * 64 + n * 16 + lr;
        const float bs = bias[col];
#pragma unroll
        for (int r = 0; r < 4; r++)
          C[(size_t)(row + r) * N + col] = acc[m][n][r] + bs;
      }
    }
  }
}

// ---------------- merged norms: y=0 q-rope, y=1 k-rope, y=2 ip_k norm, y=3 ip_v norm ----------------
__global__ __launch_bounds__(256) void k_norms(
    const float* __restrict__ Qraw, const float* __restrict__ Kraw,
    const float* __restrict__ ipKraw, const float* __restrict__ ipVraw,
    const float* __restrict__ cosp, const float* __restrict__ sinp,
    const float* __restrict__ wq, const float* __restrict__ wk,
    u16* __restrict__ Qh, u16* __restrict__ Kh,
    u16* __restrict__ ipKh, float* __restrict__ ipVn)
{
  const int y = blockIdx.y;
  const int w4 = threadIdx.x >> 6, l = threadIdx.x & 63;
  if (y < 2) {
    const int isK = y;
    const float* __restrict__ src = isK ? Kraw : Qraw;
    const float* __restrict__ wgt = isK ? wk : wq;
    u16* __restrict__ dst = isK ? Kh : Qh;
    const float scl = isK ? 1.0f : 0.08838834764831845f;  // 1/sqrt(128) folded into q
    const int row = blockIdx.x * 4 + w4;
    const int s = row / 24, h = row - s * 24;
    const float2 x = *(const float2*)&src[(size_t)s * HID + h * HD + 2 * l];
    float ss = x.x * x.x + x.y * x.y;
#pragma unroll
    for (int off = 32; off; off >>= 1) ss += __shfl_xor(ss, off);
    const float rn = rsqrtf(ss * (1.0f / 128.0f) + 1e-6f);
    const float w0 = wgt[2 * l], w1 = wgt[2 * l + 1];
    const float c0 = cosp[s * HD + 2 * l], c1 = cosp[s * HD + 2 * l + 1];
    const float s0 = sinp[s * HD + 2 * l], s1 = sinp[s * HD + 2 * l + 1];
    const float y0 = x.x * rn * w0, y1 = x.y * rn * w1;
    const float o0 = (y0 * c0 - y1 * s0) * scl;
    const float o1 = (y1 * c1 + y0 * s1) * scl;
    const uint32_t pk = (uint32_t)f2bf(o0) | ((uint32_t)f2bf(o1) << 16);
    *(uint32_t*)&dst[((size_t)h * S_LEN + s) * HD + 2 * l] = pk;
  } else {
    if (blockIdx.x >= 768) return;
    const int isV = (y == 3);
    const float* __restrict__ src = isV ? ipVraw : ipKraw;
    const int row = blockIdx.x * 4 + w4;
    const int t = row / 24, h = row - t * 24;
    const float2 x = *(const float2*)&src[(size_t)t * HID + h * HD + 2 * l];
    float ss = x.x * x.x + x.y * x.y;
#pragma unroll
    for (int off = 32; off; off >>= 1) ss += __shfl_xor(ss, off);
    const float rn = rsqrtf(ss * (1.0f / 128.0f) + 1e-5f);
    const float o0 = x.x * rn, o1 = x.y * rn;
    if (isV) {
      *(float2*)&ipVn[(size_t)t * HID + h * HD + 2 * l] = make_float2(o0, o1);
    } else {
      const uint32_t pk = (uint32_t)f2bf(o0) | ((uint32_t)f2bf(o1) << 16);
      *(uint32_t*)&ipKh[((size_t)h * 128 + t) * HD + 2 * l] = pk;
    }
  }
}

// ---------------- merged transpose f32 [S][3072] per-head -> bf16 [24][128][S] ----------------
__global__ __launch_bounds__(256) void k_transpose2(
    const float* __restrict__ Vraw, const float* __restrict__ ipVn,
    u16* __restrict__ Vt, u16* __restrict__ ipVt)
{
  const int h = blockIdx.z, d0 = blockIdx.y * 32;
  const float* __restrict__ X;
  u16* __restrict__ Y;
  int S, s0;
  if (blockIdx.x < 64) { X = Vraw; Y = Vt; S = 2048; s0 = blockIdx.x * 32; }
  else                 { X = ipVn; Y = ipVt; S = 128; s0 = (blockIdx.x - 64) * 32; }
  __shared__ float tile[32][33];
  const int c = threadIdx.x & 31, rb = threadIdx.x >> 5;
#pragma unroll
  for (int i = 0; i < 4; i++) {
    const int r = rb + i * 8;
    tile[r][c] = X[(size_t)(s0 + r) * HID + h * HD + d0 + c];
  }
  __syncthreads();
#pragma unroll
  for (int i = 0; i < 4; i++) {
    const int r = rb + i * 8;  // d-local
    Y[((size_t)h * HD + d0 + r) * S + s0 + c] = f2bf(tile[c][r]);
  }
}

// ---------------- fused flash attention (main + ip in one kernel) ----------------
// Q: [24][2048][128] bf16 (pre-scaled); K1/Vt1: main (kv=2048); K2/Vt2: ip (kv=128).
// Out: [2048][3072] f32 = attn1 + attn2, single write.
__global__ __launch_bounds__(256) void k_attn2(
    const u16* __restrict__ Q,
    const u16* __restrict__ K1, const u16* __restrict__ Vt1,
    const u16* __restrict__ K2, const u16* __restrict__ Vt2,
    float* __restrict__ Out)
{
  const int h = blockIdx.y;
  const int q0 = blockIdx.x * 64;
  const int tid = threadIdx.x, w = tid >> 6, l = tid & 63;
  const int lr = l & 15, lg = l >> 4;

  __shared__ u16 Kl[64][136];   // 272B stride: 16B aligned, 2-way banks
  __shared__ u16 Vl[128][88];   // 176B stride: 16B aligned, 2-way banks
  __shared__ u16 Pl[4][16][88]; // per-wave P tile

  bf16x8 qf[4];
  {
    const u16* qp = &Q[((size_t)h * S_LEN + q0 + w * 16 + lr) * HD];
#pragma unroll
    for (int db = 0; db < 4; db++) qf[db] = *(const bf16x8*)&qp[db * 32 + lg * 8];
  }

  auto attn_pass = [&](const u16* __restrict__ K, const u16* __restrict__ Vt,
                       int kv_len, float* m_, float* ls, f32x4* acc) {
    for (int kv0 = 0; kv0 < kv_len; kv0 += 64) {
#pragma unroll
      for (int i = 0; i < 4; i++) {
        const int c = tid + i * 256;
        { const int r = c >> 4, o = (c & 15) * 8;
          *(uint4*)&Kl[r][o] = *(const uint4*)&K[((size_t)h * kv_len + kv0 + r) * HD + o]; }
        { const int r = c >> 3, o = (c & 7) * 8;
          *(uint4*)&Vl[r][o] = *(const uint4*)&Vt[((size_t)h * HD + r) * kv_len + kv0 + o]; }
      }
      __syncthreads();

      f32x4 sf[4];
#pragma unroll
      for (int kb = 0; kb < 4; kb++) {
        f32x4 s = f32x4{0.f, 0.f, 0.f, 0.f};
#pragma unroll
        for (int db = 0; db < 4; db++) {
          bf16x8 b = *(const bf16x8*)&Kl[kb * 16 + lr][db * 32 + lg * 8];
          s = __builtin_amdgcn_mfma_f32_16x16x32_bf16(qf[db], b, s, 0, 0, 0);
        }
        sf[kb] = s;
      }

      float pv[4][4], rescv[4];
#pragma unroll
      for (int r = 0; r < 4; r++) {
        float tm = fmaxf(fmaxf(sf[0][r], sf[1][r]), fmaxf(sf[2][r], sf[3][r]));
#pragma unroll
        for (int off = 8; off; off >>= 1) tm = fmaxf(tm, __shfl_xor(tm, off));
        const float mn = fmaxf(m_[r], tm);
        const float resc = __expf(m_[r] - mn);
        float ps = 0.f;
#pragma unroll
        for (int kb = 0; kb < 4; kb++) { const float p = __expf(sf[kb][r] - mn); pv[kb][r] = p; ps += p; }
#pragma unroll
        for (int off = 8; off; off >>= 1) ps += __shfl_xor(ps, off);
        ls[r] = ls[r] * resc + ps;
        m_[r] = mn; rescv[r] = resc;
      }
#pragma unroll
      for (int nb = 0; nb < 8; nb++)
#pragma unroll
        for (int r = 0; r < 4; r++) acc[nb][r] *= rescv[r];

#pragma unroll
      for (int kb = 0; kb < 4; kb++)
#pragma unroll
        for (int r = 0; r < 4; r++)
          Pl[w][lg * 4 + r][kb * 16 + lr] = f2bf(pv[kb][r]);

      // Pl[w] is per-wave: same-wave DS ordering, no barrier needed before read-back.
#pragma unroll
      for (int kb = 0; kb < 2; kb++) {
        bf16x8 a = *(const bf16x8*)&Pl[w][lr][kb * 32 + lg * 8];
#pragma unroll
        for (int nb = 0; nb < 8; nb++) {
          bf16x8 b = *(const bf16x8*)&Vl[nb * 16 + lr][kb * 32 + lg * 8];
          acc[nb] = __builtin_amdgcn_mfma_f32_16x16x32_bf16(a, b, acc[nb], 0, 0, 0);
        }
      }
      __syncthreads();
    }
  };

  float m1[4], ls1[4], m2[4], ls2[4];
  f32x4 acc1[8], acc2[8];
#pragma unroll
  for (int r = 0; r < 4; r++) { m1[r] = -1e30f; ls1[r] = 0.f; m2[r] = -1e30f; ls2[r] = 0.f; }
#pragma unroll
  for (int nb = 0; nb < 8; nb++) { acc1[nb] = f32x4{0.f, 0.f, 0.f, 0.f}; acc2[nb] = f32x4{0.f, 0.f, 0.f, 0.f}; }

  attn_pass(K1, Vt1, 2048, m1, ls1, acc1);
  attn_pass(K2, Vt2, 128,  m2, ls2, acc2);

  float i1[4], i2[4];
#pragma unroll
  for (int r = 0; r < 4; r++) { i1[r] = 1.0f / ls1[r]; i2[r] = 1.0f / ls2[r]; }
#pragma unroll
  for (int nb = 0; nb < 8; nb++)
#pragma unroll
    for (int r = 0; r < 4; r++) {
      const int row = q0 + w * 16 + lg * 4 + r;
      const int col = h * HD + nb * 16 + lr;
      Out[(size_t)row * HID + col] = acc1[nb][r] * i1[r] + acc2[nb][r] * i2[r];
    }
}

// ---------------- launcher ----------------
extern "C" void kernel_launch(void* const* d_in, const int* in_sizes, int n_in,
                              void* d_out, int out_size, void* d_ws, size_t ws_size,
                              hipStream_t stream) {
  const float* hs   = (const float*)d_in[0];
  const float* cosp = (const float*)d_in[1];
  const float* sinp = (const float*)d_in[2];
  const float* iph  = (const float*)d_in[3];
  const float* Wq   = (const float*)d_in[4];
  const float* bq   = (const float*)d_in[5];
  const float* Wk   = (const float*)d_in[6];
  const float* bk   = (const float*)d_in[7];
  const float* Wv   = (const float*)d_in[8];
  const float* bv   = (const float*)d_in[9];
  const float* nqw  = (const float*)d_in[10];
  const float* nkw  = (const float*)d_in[11];
  const float* Wkip = (const float*)d_in[12];
  const float* Wvip = (const float*)d_in[13];
  float* out = (float*)d_out;

  uint8_t* base = (uint8_t*)d_ws;
  size_t off = 0;
  auto alloc = [&](size_t bytes) { uint8_t* p = base + off; off += (bytes + 255) & ~(size_t)255; return p; };

  u16* X16 = (u16*)alloc(2048ull * 3072 * 2);
  uint8_t* regionB = base + off;               // weights region, reused later
  u16* W16q  = (u16*)alloc(3072ull * 3072 * 2);
  u16* W16k  = (u16*)alloc(3072ull * 3072 * 2);
  u16* W16v  = (u16*)alloc(3072ull * 3072 * 2);
  u16* Wip16k = (u16*)alloc(3072ull * 4096 * 2);
  u16* Wip16v = (u16*)alloc(3072ull * 4096 * 2);
  u16* ip16   = (u16*)alloc(128ull * 4096 * 2);
  float* Qraw = (float*)alloc(2048ull * 3072 * 4);
  float* Kraw = (float*)alloc(2048ull * 3072 * 4);
  float* Vraw = (float*)alloc(2048ull * 3072 * 4);
  float* ipKraw = (float*)alloc(128ull * 3072 * 4);
  float* ipVraw = (float*)alloc(128ull * 3072 * 4);

  // region D aliases regionB (weights dead after GEMMs; stream-ordered)
  uint8_t* dp = regionB;
  auto allocD = [&](size_t bytes) { uint8_t* p = dp; dp += (bytes + 255) & ~(size_t)255; return p; };
  u16* Qh   = (u16*)allocD(24ull * 2048 * 128 * 2);
  u16* Kh   = (u16*)allocD(24ull * 2048 * 128 * 2);
  u16* Vt   = (u16*)allocD(24ull * 128 * 2048 * 2);
  u16* ipKh = (u16*)allocD(24ull * 128 * 128 * 2);
  u16* ipVt = (u16*)allocD(24ull * 128 * 128 * 2);
  float* ipVn = (float*)allocD(128ull * 3072 * 4);

  // 1. all converts + split-K accumulator zeroing, one dispatch
  ConvArgs ca;
  ca.s[0] = { hs,   (void*)X16,     1572864, 0 };
  ca.s[1] = { Wq,   (void*)W16q,    2359296, 0 };
  ca.s[2] = { Wk,   (void*)W16k,    2359296, 0 };
  ca.s[3] = { Wv,   (void*)W16v,    2359296, 0 };
  ca.s[4] = { Wkip, (void*)Wip16k,  3145728, 0 };
  ca.s[5] = { Wvip, (void*)Wip16v,  3145728, 0 };
  ca.s[6] = { iph,  (void*)ip16,    131072,  0 };
  ca.s[7] = { nullptr, (void*)ipKraw, 98304, 1 };
  ca.s[8] = { nullptr, (void*)ipVraw, 98304, 1 };
  k_convert_all<<<2048, 256, 0, stream>>>(ca);

  // 2. projections (both grids have nwg % 8 == 0 for the XCD swizzle)
  k_gemm_bt<<<dim3(16, 24, 3), 256, 0, stream>>>(X16, W16q, W16k, W16v, bq, bk, bv,
                                                 Qraw, Kraw, Vraw, 3072, 3072, 0);
  k_gemm_bt<<<dim3(4, 24, 2), 256, 0, stream>>>(ip16, Wip16k, Wip16v, Wip16v, bq, bq, bq,
                                                ipKraw, ipVraw, ipVraw, 3072, 4096, 1024);

  // 3. all norms (q/k rope + ip k/v rmsnorm), then both transposes
  k_norms<<<dim3(12288, 4), 256, 0, stream>>>(Qraw, Kraw, ipKraw, ipVraw,
                                              cosp, sinp, nqw, nkw, Qh, Kh, ipKh, ipVn);
  k_transpose2<<<dim3(68, 4, 24), 256, 0, stream>>>(Vraw, ipVn, Vt, ipVt);

  // 4. fused attention (main + ip), single out write
  k_attn2<<<dim3(32, 24), 256, 0, stream>>>(Qh, Kh, Vt, ipKh, ipVt, out);
}